// Round 3
// baseline (124.256 us; speedup 1.0000x reference)
//
#include <hip/hip_runtime.h>
#include <math.h>

// Problem constants: B=32, C=1, H=W=512, f32 in/out scalar loss.
constexpr int IMG_W  = 512;
constexpr int IMG_H  = 512;
constexpr int BATCH  = 32;
constexpr int NPIX   = BATCH * IMG_H * IMG_W;   // 8388608
constexpr int NROWS  = BATCH * IMG_H;           // 16384
constexpr int RSTRIP = 8;                        // rows per unit
constexpr int NUNIT  = NROWS / RSTRIP;           // 2048 units of 128 threads
constexpr int NTHR   = 256;                      // 2 units per block
constexpr int NBLK   = NUNIT / 2;                // 1024 blocks
constexpr int NACC   = 8;  // l1, sum(p*t), sum(p), sum(t), gx, gy, dil, ero

__global__ __launch_bounds__(NTHR) void morph_fused(
    const float* __restrict__ pred, const float* __restrict__ tgt,
    float* ws, unsigned int* counter, float* __restrict__ out)
{
    float a[NACC];
#pragma unroll
    for (int k = 0; k < NACC; ++k) a[k] = 0.f;

    const int unit    = blockIdx.x * 2 + (threadIdx.x >> 7); // 0..2047
    const int lane128 = threadIdx.x & 127;                   // float4 index in row
    const int lane64  = threadIdx.x & 63;
    const int g0      = unit * RSTRIP;                       // first global row
    const int img     = g0 >> 9;                             // /512
    const int y0      = g0 & 511;
    const int imgbase = (img << 18) + (lane128 << 2);        // img*512*512 + x

    const float4 z4 = make_float4(0.f, 0.f, 0.f, 0.f);
    float4 pp, tp, pc, tc, pn, tn;

    // prev row (zero-pad at image top)
    if (y0 != 0) {
        const int idx = imgbase + ((y0 - 1) << 9);
        pp = *(const float4*)(pred + idx);
        tp = *(const float4*)(tgt  + idx);
    } else { pp = z4; tp = z4; }
    // current row
    {
        const int idx = imgbase + (y0 << 9);
        pc = *(const float4*)(pred + idx);
        tc = *(const float4*)(tgt  + idx);
    }

    for (int r = 0; r < RSTRIP; ++r) {
        const int y = y0 + r;
        const bool hasD = (y != IMG_H - 1);
        if (hasD) {
            const int idx = imgbase + ((y + 1) << 9);
            pn = *(const float4*)(pred + idx);
            tn = *(const float4*)(tgt  + idx);
        } else { pn = z4; tn = z4; }

        // horizontal neighbors via wave shuffle; fix up wave-boundary lanes
        float pl = __shfl_up(pc.w, 1, 64);
        float tl = __shfl_up(tc.w, 1, 64);
        float pr = __shfl_down(pc.x, 1, 64);
        float tr = __shfl_down(tc.x, 1, 64);
        const int i = imgbase + (y << 9);
        if (lane64 == 0) {
            if (lane128 == 0) { pl = 0.f; tl = 0.f; }
            else              { pl = pred[i - 1]; tl = tgt[i - 1]; }
        }
        if (lane64 == 63) {
            if (lane128 == 127) { pr = 0.f; tr = 0.f; }
            else                { pr = pred[i + 4]; tr = tgt[i + 4]; }
        }
        const bool hasR = (lane128 != 127);

        const float* pcA = &pc.x; const float* tcA = &tc.x;
        const float* ppA = &pp.x; const float* tpA = &tp.x;
        const float* pnA = &pn.x; const float* tnA = &tn.x;

#pragma unroll
        for (int j = 0; j < 4; ++j) {
            const float pcj = pcA[j], tcj = tcA[j];
            a[0] += fabsf(pcj - tcj);
            a[1] += pcj * tcj;
            a[2] += pcj;
            a[3] += tcj;
            if (j < 3)
                a[4] += fabsf(fabsf(pcA[j + 1] - pcj) - fabsf(tcA[j + 1] - tcj));
            const float plj = j ? pcA[j - 1] : pl;
            const float prj = (j < 3) ? pcA[j + 1] : pr;
            const float tlj = j ? tcA[j - 1] : tl;
            const float trj = (j < 3) ? tcA[j + 1] : tr;
            // dilation: 1 - prod(1 - neighbor), cross SE, zero-padded
            float dp = 1.f - (1.f - pcj) * (1.f - plj) * (1.f - prj) * (1.f - ppA[j]) * (1.f - pnA[j]);
            float dt = 1.f - (1.f - tcj) * (1.f - tlj) * (1.f - trj) * (1.f - tpA[j]) * (1.f - tnA[j]);
            dp = fminf(fmaxf(dp, 0.f), 1.f);
            dt = fminf(fmaxf(dt, 0.f), 1.f);
            a[6] += fabsf(dp - dt);
            // erosion: prod(neighbors), OOB -> 0
            float ep = pcj * plj * prj * ppA[j] * pnA[j];
            float et = tcj * tlj * trj * tpA[j] * tnA[j];
            ep = fminf(fmaxf(ep, 0.f), 1.f);
            et = fminf(fmaxf(et, 0.f), 1.f);
            a[7] += fabsf(ep - et);
        }
        // x-gradient pair crossing the float4 boundary
        if (hasR)
            a[4] += fabsf(fabsf(pr - pcA[3]) - fabsf(tr - tcA[3]));
        // y-gradient pairs (y, y+1)
        if (hasD) {
#pragma unroll
            for (int j = 0; j < 4; ++j)
                a[5] += fabsf(fabsf(pnA[j] - pcA[j]) - fabsf(tnA[j] - tcA[j]));
        }

        pp = pc; tp = tc; pc = pn; tc = tn;
    }

    // ---- Block reduction: wave shuffle then LDS across 4 waves ----
    __shared__ float sm[NACC][NTHR / 64];
#pragma unroll
    for (int k = 0; k < NACC; ++k) {
        float v = a[k];
        for (int o = 32; o > 0; o >>= 1) v += __shfl_down(v, o, 64);
        if ((threadIdx.x & 63) == 0) sm[k][threadIdx.x >> 6] = v;
    }
    __syncthreads();
    if (threadIdx.x < NACC) {
        float v = 0.f;
#pragma unroll
        for (int w = 0; w < NTHR / 64; ++w) v += sm[threadIdx.x][w];
        ws[threadIdx.x * NBLK + blockIdx.x] = v;  // layout [acc][block]
    }

    // ---- Last-block-done finalize (release/acquire, device scope) ----
    __shared__ bool isLast;
    __threadfence();                      // release: partials visible device-wide
    __syncthreads();
    if (threadIdx.x == 0)
        isLast = (atomicAdd(counter, 1u) == NBLK - 1);
    __syncthreads();
    if (!isLast) return;
    __threadfence();                      // acquire: see all blocks' partials

    volatile const float* vws = ws;
    __shared__ double smd[NACC][NTHR / 64];
#pragma unroll
    for (int k = 0; k < NACC; ++k) {
        double v = 0.0;
        for (int idx = threadIdx.x; idx < NBLK; idx += NTHR)
            v += (double)vws[k * NBLK + idx];
        for (int o = 32; o > 0; o >>= 1) v += __shfl_down(v, o, 64);
        if ((threadIdx.x & 63) == 0) smd[k][threadIdx.x >> 6] = v;
    }
    __syncthreads();
    if (threadIdx.x == 0) {
        double r[NACC];
#pragma unroll
        for (int k = 0; k < NACC; ++k) {
            double s = 0.0;
            for (int w = 0; w < NTHR / 64; ++w) s += smd[k][w];
            r[k] = s;
        }
        const double Npix  = (double)NPIX;
        const double Ngrad = (double)BATCH * IMG_H * (IMG_W - 1);

        double total = r[0] / Npix;  // reconstruction L1
        double dice = (2.0 * r[1] + 1e-5) / (r[2] + r[3] + 1e-5);
        dice = fmin(fmax(dice, 0.0), 1.0);
        total += 0.3 * (-log(dice + 1e-8));
        total += 0.2 * 0.5 * ((r[4] + r[5]) / Ngrad);
        total += 0.2 * 0.5 * ((r[6] + r[7]) / Npix);

        out[0] = (float)fmax(total, 0.0);
    }
}

extern "C" void kernel_launch(void* const* d_in, const int* in_sizes, int n_in,
                              void* d_out, int out_size, void* d_ws, size_t ws_size,
                              hipStream_t stream) {
    const float* pred = (const float*)d_in[0];
    const float* tgt  = (const float*)d_in[1];
    float* out = (float*)d_out;
    float* ws  = (float*)d_ws;                       // partials: NACC*NBLK*4 = 32 KB
    unsigned int* counter = (unsigned int*)((char*)d_ws + NACC * NBLK * sizeof(float));

    // zero the done-counter every call (ws is poisoned once, not re-poisoned)
    hipMemsetAsync(counter, 0, sizeof(unsigned int), stream);
    morph_fused<<<NBLK, NTHR, 0, stream>>>(pred, tgt, ws, counter, out);
}

// Round 4
// 43.210 us; speedup vs baseline: 2.8756x; 2.8756x over previous
//
#include <hip/hip_runtime.h>
#include <math.h>

// Problem constants: B=32, C=1, H=W=512, f32 in/out scalar loss.
constexpr int IMG_W  = 512;
constexpr int IMG_H  = 512;
constexpr int BATCH  = 32;
constexpr int NPIX   = BATCH * IMG_H * IMG_W;   // 8388608
constexpr int NROWS  = BATCH * IMG_H;           // 16384
constexpr int RSTRIP = 4;                        // rows per unit
constexpr int NUNIT  = NROWS / RSTRIP;           // 4096 units of 128 threads
constexpr int NTHR   = 256;                      // 2 units per block
constexpr int NBLK   = NUNIT / 2;                // 2048 blocks -> 8192 waves (full)
constexpr int NACC   = 8;  // l1, sum(p*t), sum(p), sum(t), gx, gy, dil, ero

__global__ __launch_bounds__(NTHR) void morph_partials(
    const float* __restrict__ pred, const float* __restrict__ tgt,
    float* __restrict__ ws)
{
    float a[NACC];
#pragma unroll
    for (int k = 0; k < NACC; ++k) a[k] = 0.f;

    const int unit    = blockIdx.x * 2 + (threadIdx.x >> 7); // 0..NUNIT-1
    const int lane128 = threadIdx.x & 127;                   // float4 index in row
    const int lane64  = threadIdx.x & 63;
    const int g0      = unit * RSTRIP;                       // first global row
    const int img     = g0 >> 9;                             // /512
    const int y0      = g0 & 511;
    const int imgbase = (img << 18) + (lane128 << 2);        // img*512*512 + x

    const float4 z4 = make_float4(0.f, 0.f, 0.f, 0.f);
    float4 pp, tp, pc, tc, pn, tn;

    // prev row (zero-pad at image top)
    if (y0 != 0) {
        const int idx = imgbase + ((y0 - 1) << 9);
        pp = *(const float4*)(pred + idx);
        tp = *(const float4*)(tgt  + idx);
    } else { pp = z4; tp = z4; }
    // current row
    {
        const int idx = imgbase + (y0 << 9);
        pc = *(const float4*)(pred + idx);
        tc = *(const float4*)(tgt  + idx);
    }

    for (int r = 0; r < RSTRIP; ++r) {
        const int y = y0 + r;
        const bool hasD = (y != IMG_H - 1);
        if (hasD) {
            const int idx = imgbase + ((y + 1) << 9);
            pn = *(const float4*)(pred + idx);
            tn = *(const float4*)(tgt  + idx);
        } else { pn = z4; tn = z4; }

        // horizontal neighbors via wave shuffle; fix up wave-boundary lanes
        float pl = __shfl_up(pc.w, 1, 64);
        float tl = __shfl_up(tc.w, 1, 64);
        float pr = __shfl_down(pc.x, 1, 64);
        float tr = __shfl_down(tc.x, 1, 64);
        const int i = imgbase + (y << 9);
        if (lane64 == 0) {
            if (lane128 == 0) { pl = 0.f; tl = 0.f; }
            else              { pl = pred[i - 1]; tl = tgt[i - 1]; }
        }
        if (lane64 == 63) {
            if (lane128 == 127) { pr = 0.f; tr = 0.f; }
            else                { pr = pred[i + 4]; tr = tgt[i + 4]; }
        }
        const bool hasR = (lane128 != 127);

        const float* pcA = &pc.x; const float* tcA = &tc.x;
        const float* ppA = &pp.x; const float* tpA = &tp.x;
        const float* pnA = &pn.x; const float* tnA = &tn.x;

#pragma unroll
        for (int j = 0; j < 4; ++j) {
            const float pcj = pcA[j], tcj = tcA[j];
            a[0] += fabsf(pcj - tcj);
            a[1] += pcj * tcj;
            a[2] += pcj;
            a[3] += tcj;
            if (j < 3)
                a[4] += fabsf(fabsf(pcA[j + 1] - pcj) - fabsf(tcA[j + 1] - tcj));
            const float plj = j ? pcA[j - 1] : pl;
            const float prj = (j < 3) ? pcA[j + 1] : pr;
            const float tlj = j ? tcA[j - 1] : tl;
            const float trj = (j < 3) ? tcA[j + 1] : tr;
            // dilation: 1 - prod(1 - neighbor), cross SE, zero-padded
            float dp = 1.f - (1.f - pcj) * (1.f - plj) * (1.f - prj) * (1.f - ppA[j]) * (1.f - pnA[j]);
            float dt = 1.f - (1.f - tcj) * (1.f - tlj) * (1.f - trj) * (1.f - tpA[j]) * (1.f - tnA[j]);
            dp = fminf(fmaxf(dp, 0.f), 1.f);
            dt = fminf(fmaxf(dt, 0.f), 1.f);
            a[6] += fabsf(dp - dt);
            // erosion: prod(neighbors), OOB -> 0
            float ep = pcj * plj * prj * ppA[j] * pnA[j];
            float et = tcj * tlj * trj * tpA[j] * tnA[j];
            ep = fminf(fmaxf(ep, 0.f), 1.f);
            et = fminf(fmaxf(et, 0.f), 1.f);
            a[7] += fabsf(ep - et);
        }
        // x-gradient pair crossing the float4 boundary
        if (hasR)
            a[4] += fabsf(fabsf(pr - pcA[3]) - fabsf(tr - tcA[3]));
        // y-gradient pairs (y, y+1)
        if (hasD) {
#pragma unroll
            for (int j = 0; j < 4; ++j)
                a[5] += fabsf(fabsf(pnA[j] - pcA[j]) - fabsf(tnA[j] - tcA[j]));
        }

        pp = pc; tp = tc; pc = pn; tc = tn;
    }

    // Block reduction: wave shuffle then LDS across 4 waves.
    __shared__ float sm[NACC][NTHR / 64];
#pragma unroll
    for (int k = 0; k < NACC; ++k) {
        float v = a[k];
        for (int o = 32; o > 0; o >>= 1) v += __shfl_down(v, o, 64);
        if ((threadIdx.x & 63) == 0) sm[k][threadIdx.x >> 6] = v;
    }
    __syncthreads();
    if (threadIdx.x < NACC) {
        float v = 0.f;
#pragma unroll
        for (int w = 0; w < NTHR / 64; ++w) v += sm[threadIdx.x][w];
        ws[threadIdx.x * NBLK + blockIdx.x] = v;  // layout [acc][block]
    }
}

// One block reduces the per-block partials (double) and applies the formula.
__global__ __launch_bounds__(NTHR) void morph_final(
    const float* __restrict__ ws, float* __restrict__ out)
{
    __shared__ double sm[NACC][NTHR / 64];
#pragma unroll
    for (int k = 0; k < NACC; ++k) {
        double v = 0.0;
        for (int idx = threadIdx.x; idx < NBLK; idx += NTHR)
            v += (double)ws[k * NBLK + idx];
        for (int o = 32; o > 0; o >>= 1) v += __shfl_down(v, o, 64);
        if ((threadIdx.x & 63) == 0) sm[k][threadIdx.x >> 6] = v;
    }
    __syncthreads();
    if (threadIdx.x == 0) {
        double r[NACC];
#pragma unroll
        for (int k = 0; k < NACC; ++k) {
            double s = 0.0;
            for (int w = 0; w < NTHR / 64; ++w) s += sm[k][w];
            r[k] = s;
        }
        const double Npix  = (double)NPIX;
        const double Ngrad = (double)BATCH * IMG_H * (IMG_W - 1);

        double total = r[0] / Npix;  // reconstruction L1
        double dice = (2.0 * r[1] + 1e-5) / (r[2] + r[3] + 1e-5);
        dice = fmin(fmax(dice, 0.0), 1.0);
        total += 0.3 * (-log(dice + 1e-8));
        total += 0.2 * 0.5 * ((r[4] + r[5]) / Ngrad);
        total += 0.2 * 0.5 * ((r[6] + r[7]) / Npix);

        out[0] = (float)fmax(total, 0.0);
    }
}

extern "C" void kernel_launch(void* const* d_in, const int* in_sizes, int n_in,
                              void* d_out, int out_size, void* d_ws, size_t ws_size,
                              hipStream_t stream) {
    const float* pred = (const float*)d_in[0];
    const float* tgt  = (const float*)d_in[1];
    float* out = (float*)d_out;
    float* ws  = (float*)d_ws;   // NACC*NBLK*4 = 64 KB

    morph_partials<<<NBLK, NTHR, 0, stream>>>(pred, tgt, ws);
    morph_final<<<1, NTHR, 0, stream>>>(ws, out);
}

// Round 5
// 33.484 us; speedup vs baseline: 3.7109x; 1.2905x over previous
//
#include <hip/hip_runtime.h>
#include <math.h>

// Problem constants: B=32, C=1, H=W=512, f32 in/out scalar loss.
constexpr int IMG_W  = 512;
constexpr int IMG_H  = 512;
constexpr int BATCH  = 32;
constexpr int NPIX   = BATCH * IMG_H * IMG_W;   // 8388608
constexpr int NROWS  = BATCH * IMG_H;           // 16384
constexpr int RSTRIP = 16;                       // rows per unit (1.125x read multiplier)
constexpr int NUNIT  = NROWS / RSTRIP;           // 1024 units of 128 threads
constexpr int NTHR   = 256;                      // 2 units per block
constexpr int NBLK   = NUNIT / 2;                // 512 blocks -> 2048 waves, all co-resident
constexpr int NXCD   = 8;
constexpr int NACC   = 8;  // l1, sum(p*t), sum(p), sum(t), gx, gy, dil, ero

__global__ __launch_bounds__(NTHR) void morph_partials(
    const float* __restrict__ pred, const float* __restrict__ tgt,
    float* __restrict__ ws)
{
    float a[NACC];
#pragma unroll
    for (int k = 0; k < NACC; ++k) a[k] = 0.f;

    // XCD-chunked bijective swizzle (NBLK % 8 == 0): consecutive swz values
    // (adjacent strips) land on the SAME XCD -> boundary-row re-reads hit L2.
    const int swz = (blockIdx.x % NXCD) * (NBLK / NXCD) + blockIdx.x / NXCD;

    const int unit    = swz * 2 + (threadIdx.x >> 7);        // 0..NUNIT-1
    const int lane128 = threadIdx.x & 127;                   // float4 index in row
    const int lane64  = threadIdx.x & 63;
    const int g0      = unit * RSTRIP;                       // first global row
    const int img     = g0 >> 9;                             // /512
    const int y0      = g0 & 511;
    const int imgbase = (img << 18) + (lane128 << 2);        // img*512*512 + x

    const float4 z4 = make_float4(0.f, 0.f, 0.f, 0.f);
    float4 pp, tp, pc, tc, pn, tn;

    // prev row (zero-pad at image top)
    if (y0 != 0) {
        const int idx = imgbase + ((y0 - 1) << 9);
        pp = *(const float4*)(pred + idx);
        tp = *(const float4*)(tgt  + idx);
    } else { pp = z4; tp = z4; }
    // current row
    {
        const int idx = imgbase + (y0 << 9);
        pc = *(const float4*)(pred + idx);
        tc = *(const float4*)(tgt  + idx);
    }

    for (int r = 0; r < RSTRIP; ++r) {
        const int y = y0 + r;
        const bool hasD = (y != IMG_H - 1);
        if (hasD) {
            const int idx = imgbase + ((y + 1) << 9);
            pn = *(const float4*)(pred + idx);
            tn = *(const float4*)(tgt  + idx);
        } else { pn = z4; tn = z4; }

        // horizontal neighbors via wave shuffle; fix up wave-boundary lanes
        float pl = __shfl_up(pc.w, 1, 64);
        float tl = __shfl_up(tc.w, 1, 64);
        float pr = __shfl_down(pc.x, 1, 64);
        float tr = __shfl_down(tc.x, 1, 64);
        const int i = imgbase + (y << 9);
        if (lane64 == 0) {
            if (lane128 == 0) { pl = 0.f; tl = 0.f; }
            else              { pl = pred[i - 1]; tl = tgt[i - 1]; }
        }
        if (lane64 == 63) {
            if (lane128 == 127) { pr = 0.f; tr = 0.f; }
            else                { pr = pred[i + 4]; tr = tgt[i + 4]; }
        }
        const bool hasR = (lane128 != 127);

        const float* pcA = &pc.x; const float* tcA = &tc.x;
        const float* ppA = &pp.x; const float* tpA = &tp.x;
        const float* pnA = &pn.x; const float* tnA = &tn.x;

#pragma unroll
        for (int j = 0; j < 4; ++j) {
            const float pcj = pcA[j], tcj = tcA[j];
            a[0] += fabsf(pcj - tcj);
            a[1] += pcj * tcj;
            a[2] += pcj;
            a[3] += tcj;
            if (j < 3)
                a[4] += fabsf(fabsf(pcA[j + 1] - pcj) - fabsf(tcA[j + 1] - tcj));
            const float plj = j ? pcA[j - 1] : pl;
            const float prj = (j < 3) ? pcA[j + 1] : pr;
            const float tlj = j ? tcA[j - 1] : tl;
            const float trj = (j < 3) ? tcA[j + 1] : tr;
            // dilation: 1 - prod(1 - neighbor), cross SE, zero-padded
            float dp = 1.f - (1.f - pcj) * (1.f - plj) * (1.f - prj) * (1.f - ppA[j]) * (1.f - pnA[j]);
            float dt = 1.f - (1.f - tcj) * (1.f - tlj) * (1.f - trj) * (1.f - tpA[j]) * (1.f - tnA[j]);
            dp = fminf(fmaxf(dp, 0.f), 1.f);
            dt = fminf(fmaxf(dt, 0.f), 1.f);
            a[6] += fabsf(dp - dt);
            // erosion: prod(neighbors), OOB -> 0
            float ep = pcj * plj * prj * ppA[j] * pnA[j];
            float et = tcj * tlj * trj * tpA[j] * tnA[j];
            ep = fminf(fmaxf(ep, 0.f), 1.f);
            et = fminf(fmaxf(et, 0.f), 1.f);
            a[7] += fabsf(ep - et);
        }
        // x-gradient pair crossing the float4 boundary
        if (hasR)
            a[4] += fabsf(fabsf(pr - pcA[3]) - fabsf(tr - tcA[3]));
        // y-gradient pairs (y, y+1)
        if (hasD) {
#pragma unroll
            for (int j = 0; j < 4; ++j)
                a[5] += fabsf(fabsf(pnA[j] - pcA[j]) - fabsf(tnA[j] - tcA[j]));
        }

        pp = pc; tp = tc; pc = pn; tc = tn;
    }

    // Block reduction: wave shuffle then LDS across 4 waves.
    __shared__ float sm[NACC][NTHR / 64];
#pragma unroll
    for (int k = 0; k < NACC; ++k) {
        float v = a[k];
        for (int o = 32; o > 0; o >>= 1) v += __shfl_down(v, o, 64);
        if ((threadIdx.x & 63) == 0) sm[k][threadIdx.x >> 6] = v;
    }
    __syncthreads();
    if (threadIdx.x < NACC) {
        float v = 0.f;
#pragma unroll
        for (int w = 0; w < NTHR / 64; ++w) v += sm[threadIdx.x][w];
        ws[threadIdx.x * NBLK + blockIdx.x] = v;  // layout [acc][block]
    }
}

// One block reduces the per-block partials (double) and applies the formula.
__global__ __launch_bounds__(NTHR) void morph_final(
    const float* __restrict__ ws, float* __restrict__ out)
{
    __shared__ double sm[NACC][NTHR / 64];
#pragma unroll
    for (int k = 0; k < NACC; ++k) {
        double v = 0.0;
        for (int idx = threadIdx.x; idx < NBLK; idx += NTHR)
            v += (double)ws[k * NBLK + idx];
        for (int o = 32; o > 0; o >>= 1) v += __shfl_down(v, o, 64);
        if ((threadIdx.x & 63) == 0) sm[k][threadIdx.x >> 6] = v;
    }
    __syncthreads();
    if (threadIdx.x == 0) {
        double r[NACC];
#pragma unroll
        for (int k = 0; k < NACC; ++k) {
            double s = 0.0;
            for (int w = 0; w < NTHR / 64; ++w) s += sm[k][w];
            r[k] = s;
        }
        const double Npix  = (double)NPIX;
        const double Ngrad = (double)BATCH * IMG_H * (IMG_W - 1);

        double total = r[0] / Npix;  // reconstruction L1
        double dice = (2.0 * r[1] + 1e-5) / (r[2] + r[3] + 1e-5);
        dice = fmin(fmax(dice, 0.0), 1.0);
        total += 0.3 * (-log(dice + 1e-8));
        total += 0.2 * 0.5 * ((r[4] + r[5]) / Ngrad);
        total += 0.2 * 0.5 * ((r[6] + r[7]) / Npix);

        out[0] = (float)fmax(total, 0.0);
    }
}

extern "C" void kernel_launch(void* const* d_in, const int* in_sizes, int n_in,
                              void* d_out, int out_size, void* d_ws, size_t ws_size,
                              hipStream_t stream) {
    const float* pred = (const float*)d_in[0];
    const float* tgt  = (const float*)d_in[1];
    float* out = (float*)d_out;
    float* ws  = (float*)d_ws;   // NACC*NBLK*4 = 16 KB

    morph_partials<<<NBLK, NTHR, 0, stream>>>(pred, tgt, ws);
    morph_final<<<1, NTHR, 0, stream>>>(ws, out);
}

// Round 6
// 29.477 us; speedup vs baseline: 4.2154x; 1.1360x over previous
//
#include <hip/hip_runtime.h>
#include <math.h>

// Problem constants: B=32, C=1, H=W=512, f32 in/out scalar loss.
constexpr int IMG_W  = 512;
constexpr int IMG_H  = 512;
constexpr int BATCH  = 32;
constexpr int NPIX   = BATCH * IMG_H * IMG_W;   // 8388608
constexpr int NROWS  = BATCH * IMG_H;           // 16384
constexpr int BROWS  = 64;                       // rows per block (4 units x 16)
constexpr int NTHR   = 512;                      // 4 units of 128 threads
constexpr int NBLK   = NROWS / BROWS;            // 256 blocks -> 2048 waves
constexpr int NXCD   = 8;
constexpr int NACC   = 8;  // l1, sum(p*t), sum(p), sum(t), gx, gy, dil, ero

__device__ __forceinline__ void row_compute(
    const float4& pU, const float4& tU,   // row above (y-1), zero at image top
    const float4& pC, const float4& tC,   // current row y
    const float4& pD, const float4& tD,   // row below (y+1), zero at image bottom
    int gi, int lane128, int lane64, bool gyok,
    const float* __restrict__ pred, const float* __restrict__ tgt,
    float* a)
{
    // horizontal neighbors via wave shuffle; fix up wave-boundary lanes
    float pl = __shfl_up(pC.w, 1, 64);
    float tl = __shfl_up(tC.w, 1, 64);
    float pr = __shfl_down(pC.x, 1, 64);
    float tr = __shfl_down(tC.x, 1, 64);
    if (lane64 == 0) {
        if (lane128 == 0) { pl = 0.f; tl = 0.f; }
        else              { pl = pred[gi - 1]; tl = tgt[gi - 1]; }
    }
    if (lane64 == 63) {
        if (lane128 == 127) { pr = 0.f; tr = 0.f; }
        else                { pr = pred[gi + 4]; tr = tgt[gi + 4]; }
    }
    const bool hasR = (lane128 != 127);

    const float* pcA = &pC.x; const float* tcA = &tC.x;
    const float* ppA = &pU.x; const float* tpA = &tU.x;
    const float* pnA = &pD.x; const float* tnA = &tD.x;

#pragma unroll
    for (int j = 0; j < 4; ++j) {
        const float pcj = pcA[j], tcj = tcA[j];
        a[0] += fabsf(pcj - tcj);
        a[1] += pcj * tcj;
        a[2] += pcj;
        a[3] += tcj;
        if (j < 3)
            a[4] += fabsf(fabsf(pcA[j + 1] - pcj) - fabsf(tcA[j + 1] - tcj));
        const float plj = j ? pcA[j - 1] : pl;
        const float prj = (j < 3) ? pcA[j + 1] : pr;
        const float tlj = j ? tcA[j - 1] : tl;
        const float trj = (j < 3) ? tcA[j + 1] : tr;
        // dilation: 1 - prod(1 - neighbor), cross SE, zero-padded
        float dp = 1.f - (1.f - pcj) * (1.f - plj) * (1.f - prj) * (1.f - ppA[j]) * (1.f - pnA[j]);
        float dt = 1.f - (1.f - tcj) * (1.f - tlj) * (1.f - trj) * (1.f - tpA[j]) * (1.f - tnA[j]);
        dp = fminf(fmaxf(dp, 0.f), 1.f);
        dt = fminf(fmaxf(dt, 0.f), 1.f);
        a[6] += fabsf(dp - dt);
        // erosion: prod(neighbors), OOB -> 0
        float ep = pcj * plj * prj * ppA[j] * pnA[j];
        float et = tcj * tlj * trj * tpA[j] * tnA[j];
        ep = fminf(fmaxf(ep, 0.f), 1.f);
        et = fminf(fmaxf(et, 0.f), 1.f);
        a[7] += fabsf(ep - et);
    }
    // x-gradient pair crossing the float4 boundary
    if (hasR)
        a[4] += fabsf(fabsf(pr - pcA[3]) - fabsf(tr - tcA[3]));
    // y-gradient pairs (y, y+1) — owned by cur row, uses the below row
    if (gyok) {
#pragma unroll
        for (int j = 0; j < 4; ++j)
            a[5] += fabsf(fabsf(pnA[j] - pcA[j]) - fabsf(tnA[j] - tcA[j]));
    }
}

__global__ __launch_bounds__(NTHR) void morph_partials(
    const float* __restrict__ pred, const float* __restrict__ tgt,
    float* __restrict__ ws)
{
    float a[NACC];
#pragma unroll
    for (int k = 0; k < NACC; ++k) a[k] = 0.f;

    // XCD-chunked bijective swizzle (NBLK % 8 == 0): adjacent strips same XCD.
    const int swz = (blockIdx.x % NXCD) * (NBLK / NXCD) + blockIdx.x / NXCD;

    const int unit    = threadIdx.x >> 7;     // 0..3
    const int lane128 = threadIdx.x & 127;
    const int lane64  = threadIdx.x & 63;
    const bool down   = !(unit & 1);          // units 0,2 walk down; 1,3 walk up
    const int gb      = swz * BROWS;          // block's first global row
    const int img     = gb >> 9;
    const int yb      = gb & 511;             // first row within image (0..448, step 64)
    const int imgbase = (img << 18) + (lane128 << 2);

    __shared__ float4 xch[4][2][128];         // boundary-row exchange (16 KB)
    __shared__ float  smr[NACC][NTHR / 64];

    const float4 z4 = make_float4(0.f, 0.f, 0.f, 0.f);
    float4 pU = z4, tU = z4, pC, tC, pD = z4, tD = z4;

    // ---- init: load first cur row, publish it for the init exchange ----
    const int yl0 = down ? unit * 16 : unit * 16 + 15;
    {
        const int idx = imgbase + ((yb + yl0) << 9);
        pC = *(const float4*)(pred + idx);
        tC = *(const float4*)(tgt  + idx);
    }
    xch[unit][0][lane128] = pC;
    xch[unit][1][lane128] = tC;
    __syncthreads();
    if (unit == 0) {                          // halo above (zero at image top)
        if (yb != 0) {
            const int idx = imgbase + ((yb - 1) << 9);
            pU = *(const float4*)(pred + idx);
            tU = *(const float4*)(tgt  + idx);
        }
    } else if (unit == 1) {                   // below = u2's first cur (row yb+32)
        pD = xch[2][0][lane128]; tD = xch[2][1][lane128];
    } else if (unit == 2) {                   // above = u1's first cur (row yb+31)
        pU = xch[1][0][lane128]; tU = xch[1][1][lane128];
    } else {                                  // halo below (zero at image bottom)
        if (yb != IMG_H - BROWS) {
            const int idx = imgbase + ((yb + BROWS) << 9);
            pD = *(const float4*)(pred + idx);
            tD = *(const float4*)(tgt  + idx);
        }
    }

    for (int r = 0; r < 16; ++r) {
        const int yl = down ? unit * 16 + r : unit * 16 + 15 - r;
        const int yi = yb + yl;               // row within image, 0..511
        // fetch the fresh neighbor row
        if (r == 15) {                        // boundary exchange u0<->u1, u2<->u3
            __syncthreads();                  // init-exchange reads done
            xch[unit][0][lane128] = pC;
            xch[unit][1][lane128] = tC;
            __syncthreads();
            const int pair = unit ^ 1;
            if (down) { pD = xch[pair][0][lane128]; tD = xch[pair][1][lane128]; }
            else      { pU = xch[pair][0][lane128]; tU = xch[pair][1][lane128]; }
        } else {
            const int ny  = down ? yi + 1 : yi - 1;
            const int idx = imgbase + (ny << 9);
            if (down) { pD = *(const float4*)(pred + idx); tD = *(const float4*)(tgt + idx); }
            else      { pU = *(const float4*)(pred + idx); tU = *(const float4*)(tgt + idx); }
        }
        const bool gyok = (yi != IMG_H - 1);  // only u3 r==0 at image bottom is false
        const int  gi   = imgbase + (yi << 9);
        row_compute(pU, tU, pC, tC, pD, tD, gi, lane128, lane64, gyok, pred, tgt, a);
        // shift the rolling window
        if (down) { pU = pC; tU = tC; pC = pD; tC = tD; }
        else      { pD = pC; tD = tC; pC = pU; tC = tU; }
    }

    // ---- block reduction: wave shuffle then LDS across 8 waves ----
#pragma unroll
    for (int k = 0; k < NACC; ++k) {
        float v = a[k];
        for (int o = 32; o > 0; o >>= 1) v += __shfl_down(v, o, 64);
        if ((threadIdx.x & 63) == 0) smr[k][threadIdx.x >> 6] = v;
    }
    __syncthreads();
    if (threadIdx.x < NACC) {
        float v = 0.f;
#pragma unroll
        for (int w = 0; w < NTHR / 64; ++w) v += smr[threadIdx.x][w];
        ws[threadIdx.x * NBLK + blockIdx.x] = v;  // layout [acc][block]
    }
}

// One block reduces the per-block partials (double) and applies the formula.
__global__ __launch_bounds__(256) void morph_final(
    const float* __restrict__ ws, float* __restrict__ out)
{
    __shared__ double sm[NACC][256 / 64];
#pragma unroll
    for (int k = 0; k < NACC; ++k) {
        double v = 0.0;
        for (int idx = threadIdx.x; idx < NBLK; idx += 256)
            v += (double)ws[k * NBLK + idx];
        for (int o = 32; o > 0; o >>= 1) v += __shfl_down(v, o, 64);
        if ((threadIdx.x & 63) == 0) sm[k][threadIdx.x >> 6] = v;
    }
    __syncthreads();
    if (threadIdx.x == 0) {
        double r[NACC];
#pragma unroll
        for (int k = 0; k < NACC; ++k) {
            double s = 0.0;
            for (int w = 0; w < 256 / 64; ++w) s += sm[k][w];
            r[k] = s;
        }
        const double Npix  = (double)NPIX;
        const double Ngrad = (double)BATCH * IMG_H * (IMG_W - 1);

        double total = r[0] / Npix;  // reconstruction L1
        double dice = (2.0 * r[1] + 1e-5) / (r[2] + r[3] + 1e-5);
        dice = fmin(fmax(dice, 0.0), 1.0);
        total += 0.3 * (-log(dice + 1e-8));
        total += 0.2 * 0.5 * ((r[4] + r[5]) / Ngrad);
        total += 0.2 * 0.5 * ((r[6] + r[7]) / Npix);

        out[0] = (float)fmax(total, 0.0);
    }
}

extern "C" void kernel_launch(void* const* d_in, const int* in_sizes, int n_in,
                              void* d_out, int out_size, void* d_ws, size_t ws_size,
                              hipStream_t stream) {
    const float* pred = (const float*)d_in[0];
    const float* tgt  = (const float*)d_in[1];
    float* out = (float*)d_out;
    float* ws  = (float*)d_ws;   // NACC*NBLK*4 = 8 KB

    morph_partials<<<NBLK, NTHR, 0, stream>>>(pred, tgt, ws);
    morph_final<<<1, 256, 0, stream>>>(ws, out);
}